// Round 20
// baseline (309.111 us; speedup 1.0000x reference)
//
#include <hip/hip_runtime.h>
#include <cstdint>

// Problem constants (fixed by the reference)
static constexpr int NN = 50000;   // nodes
static constexpr int NE = 800000;  // edges
static constexpr int NG = 512;     // graphs
static constexpr int NR = 19;      // relations
static constexpr int DD = 64;      // hidden dim
static constexpr int EMB = 65;
static constexpr int HID = 128;
static constexpr int FP = 166;
static constexpr int NEP = NE + NR * 16;   // padded edge capacity (etype bins)
static constexpr int NMSG = NE + 304;      // msg rows incl. pad dump zone
static constexpr int SCB5 = (NN + 511) / 512;      // 98
static constexpr int EB5  = (NE + 511) / 512;      // 1563
static constexpr int ET5  = (NE + 4095) / 4096;    // 196
static constexpr int WPB512 = (2 * NR * 8 * 64 + 511) / 512;  // 38

typedef __fp16 h2 __attribute__((ext_vector_type(2)));
typedef _Float16 F16x2 __attribute__((ext_vector_type(2)));
typedef _Float16 hf8 __attribute__((ext_vector_type(8)));
typedef float f32x4 __attribute__((ext_vector_type(4)));
typedef unsigned u32x4 __attribute__((ext_vector_type(4)));
typedef int i32x4 __attribute__((ext_vector_type(4)));

union U4H8 { u32x4 u; hf8 h; };

__device__ __forceinline__ hf8 as_hf8(u32x4 u) { U4H8 c; c.u = u; return c.h; }

__device__ __forceinline__ float dot2f(unsigned a, unsigned b, float c) {
    union { unsigned u; h2 h; } ua, ub;
    ua.u = a; ub.u = b;
    return __builtin_amdgcn_fdot2(ua.h, ub.h, c, false);
}

__device__ __forceinline__ unsigned pack2(float a, float b) {
    union { h2 h; unsigned u; } r;
    r.h = __builtin_amdgcn_cvt_pkrtz(a, b);
    return r.u;
}

__device__ __forceinline__ void pkAtomicAdd(unsigned* addr, float lo, float hi) {
    unsigned u = pack2(lo, hi);
#if __has_builtin(__builtin_amdgcn_global_atomic_fadd_v2f16)
    union { unsigned u; F16x2 h; } c; c.u = u;
    __builtin_amdgcn_global_atomic_fadd_v2f16((F16x2*)addr, c.h);
#else
    asm volatile("global_atomic_pk_add_f16 %0, %1, off" :: "v"(addr), "v"(u) : "memory");
#endif
}

__device__ __forceinline__ float half_at(unsigned v, int idx) {
    union { unsigned u; h2 h; } c; c.u = v;
    return (float)c.h[idx];
}

// first index in sorted n2g with n2g[idx] >= key
__device__ __forceinline__ int lbound(const int* __restrict__ a, int key) {
    int lo = 0, hi = NN;
    while (lo < hi) {
        int mid = (lo + hi) >> 1;
        if (a[mid] < key) lo = mid + 1; else hi = mid;
    }
    return lo;
}

// ====== D1: ketcnt (blocks [0,ET5), block-combined flush) || degree hist (1 edge/thread) =======
__global__ __launch_bounds__(512) void kd1(const int* __restrict__ dst, const int* __restrict__ et,
                                           int* __restrict__ degi, int* __restrict__ cnt19) {
    const int b = blockIdx.x;
    const int t = threadIdx.x;
    if (b < ET5) {
        __shared__ int lcnt[8][NR];
        const int lane = t & 63;
        const int wid = t >> 6;   // 0..7
        const int wbase = (b * 8 + wid) * 512;
        int cnt = 0;
#pragma unroll
        for (int i = 0; i < 8; ++i) {
            int e = wbase + i * 64 + lane;
            int myet = (e < NE) ? et[e] : -1;
#pragma unroll
            for (int r = 0; r < NR; ++r) {
                unsigned long long bm = __ballot(myet == r);
                if (lane == r) cnt += (int)__popcll(bm);
            }
        }
        if (lane < NR) lcnt[wid][lane] = cnt;
        __syncthreads();
        if (t < NR) {
            int s = 0;
#pragma unroll
            for (int wv = 0; wv < 8; ++wv) s += lcnt[wv][t];
            if (s) atomicAdd(&cnt19[t], s);
        }
    } else {
        int e = (b - ET5) * 512 + t;
        if (e < NE) atomicAdd(&degi[dst[e]], 1);
    }
}

// ===== D2: kscanA [0,SCB5) || scan19+pad (b==SCB5, pads get perm=NE dump) || Wpack =============
__global__ __launch_bounds__(512) void kd2(const int* __restrict__ degi, int* __restrict__ part,
                                           const int* __restrict__ cnt19, int* __restrict__ pbase,
                                           int* __restrict__ cur19, int* __restrict__ batchptr,
                                           unsigned* __restrict__ hpk0, unsigned* __restrict__ hpk1,
                                           unsigned short* __restrict__ sdp, unsigned short* __restrict__ dsp,
                                           int* __restrict__ perm,
                                           const float* __restrict__ W1, const float* __restrict__ W2,
                                           unsigned* __restrict__ wpk1, unsigned* __restrict__ wpk2) {
    const int b = blockIdx.x;
    const int t = threadIdx.x;
    if (b < SCB5) {
        __shared__ int red[512];
        int idx = b * 512 + t;
        red[t] = (idx < NN) ? degi[idx] : 0;
        __syncthreads();
#pragma unroll
        for (int s = 256; s > 0; s >>= 1) {
            if (t < s) red[t] += red[t + s];
            __syncthreads();
        }
        if (t == 0) part[b] = red[0];
    } else if (b == SCB5) {
        __shared__ int spb[NR + 1];
        if (t == 0) {
            int run = 0;
            for (int r = 0; r < NR; ++r) {
                spb[r] = run; pbase[r] = run; cur19[r] = run; batchptr[r] = run >> 4;
                run += (cnt19[r] + 15) & ~15;
            }
            spb[NR] = run; pbase[NR] = run; batchptr[NR] = run >> 4;
        }
        if (t < 32) hpk0[(size_t)NN * 32 + t] = 0;
        else if (t < 64) hpk1[(size_t)NN * 32 + (t - 32)] = 0;
        __syncthreads();
        int r = t >> 4, i = t & 15;
        if (r < NR) {
            int cnt = cnt19[r];
            int tail = spb[r + 1] - spb[r] - cnt;
            if (i < tail) {
                int pos = spb[r] + cnt + i;
                sdp[pos] = (unsigned short)NN;   // zero h row
                dsp[pos] = (unsigned short)NN;   // fallback dump row
                perm[pos] = NE;                  // dump msg row (never read)
            }
        }
    } else {
        int tt = (b - SCB5 - 1) * 512 + t;
        if (tt >= 2 * NR * 8 * 64) return;
        int which = tt >= NR * 8 * 64;
        int t2 = tt - which * NR * 8 * 64;
        const float* W = which ? W2 : W1;
        unsigned* wpk = which ? wpk2 : wpk1;
        int lane = t2 & 63;
        int f = (t2 >> 6) & 7;
        int r = t2 >> 9;
        int kh = f >> 2, ct = f & 3;
        int kbase = kh * 32 + (lane >> 4) * 8;
        int col = (ct >> 1) * 32 + 2 * (lane & 15) + (ct & 1);
        const float* wr = W + (size_t)r * DD * DD;
        u32x4 out;
#pragma unroll
        for (int p = 0; p < 4; ++p)
            out[p] = pack2(wr[(kbase + 2 * p) * DD + col], wr[(kbase + 2 * p + 1) * DD + col]);
        *((u32x4*)wpk + t2) = out;
    }
}

// ================= D3: kscanBC alone (98 blocks) ==============================================
__global__ __launch_bounds__(512) void kd3(const int* __restrict__ degi, const int* __restrict__ part,
                                           int* __restrict__ dstoff, int* __restrict__ cur) {
    __shared__ int sp[512];
    __shared__ int s[512];
    const int b = blockIdx.x;
    const int t = threadIdx.x;
    sp[t] = (t < SCB5) ? part[t] : 0;
    int idx = b * 512 + t;
    int v = (idx < NN) ? degi[idx] : 0;
    s[t] = v;
    __syncthreads();
#pragma unroll
    for (int d = 1; d < 512; d <<= 1) {
        int x1 = (t >= d) ? sp[t - d] : 0;
        int x2 = (t >= d) ? s[t - d] : 0;
        __syncthreads();
        sp[t] += x1;
        s[t] += x2;
        __syncthreads();
    }
    int boff = (b == 0) ? 0 : sp[b - 1];
    int excl = boff + ((t == 0) ? 0 : s[t - 1]);
    if (idx < NN) { dstoff[idx] = excl; cur[idx] = excl; }
    if (idx == NN - 1) { dstoff[NN] = NE; cur[NN] = NE; }
}

// ==== D4: fused counting-sort scatter + CSR slot atomic + perm + layer-0 msg0 ==================
__global__ __launch_bounds__(512) void kd4(const int* __restrict__ src, const int* __restrict__ dst,
                                           const int* __restrict__ et, int* __restrict__ cur19,
                                           const int* __restrict__ degi, int* __restrict__ cur,
                                           unsigned short* __restrict__ sdp, unsigned short* __restrict__ dsp,
                                           int* __restrict__ perm, unsigned* __restrict__ msg0) {
    __shared__ int wcnt[8][NR];
    __shared__ int lb[NR];
    __shared__ int woff[8][NR];
    const int b = blockIdx.x;
    const int t = threadIdx.x;
    const int lane = t & 63;
    const int wid = t >> 6;   // 0..7
    int e = b * 512 + t;
    int myet = -1, d = 0, sv = 0;
    if (e < NE) { myet = et[e]; d = dst[e]; sv = src[e]; }
    const unsigned long long below = (lane == 63) ? ~0ull >> 1 : ((1ull << lane) - 1);
    int myrank = 0, cnt_r = 0;
#pragma unroll
    for (int r = 0; r < NR; ++r) {
        unsigned long long m = __ballot(myet == r);
        if (myet == r) myrank = (int)__popcll(m & below);
        if (lane == r) cnt_r = (int)__popcll(m);
    }
    if (lane < NR) wcnt[wid][lane] = cnt_r;
    __syncthreads();
    if (t < NR) {
        int run = 0, c[8];
#pragma unroll
        for (int wv = 0; wv < 8; ++wv) { c[wv] = wcnt[wv][t]; }
#pragma unroll
        for (int wv = 0; wv < 8; ++wv) { woff[wv][t] = run; run += c[wv]; }
        lb[t] = run ? atomicAdd(&cur19[t], run) : 0;
    }
    __syncthreads();
    if (e < NE) {
        int pos = lb[myet] + woff[wid][myet] + myrank;
        sdp[pos] = (unsigned short)sv;
        if (dsp) dsp[pos] = (unsigned short)d;
        int deg = degi[sv];
        int slot = atomicAdd(&cur[d], 1);
        perm[pos] = slot;
        msg0[slot] = ((unsigned)myet << 16) | (unsigned)deg;
    }
}

// ---------------- layer 0 (store path): h0 = relu(sum_rows deg*W0[et] + deg*L0 + b0) -----------
__global__ __launch_bounds__(256) void kf0m(const unsigned* __restrict__ msg0, const int* __restrict__ dstoff,
                                            const float* __restrict__ W0, const float* __restrict__ L0,
                                            const float* __restrict__ b0, unsigned* __restrict__ hpk0) {
    __shared__ float Lw[NR * DD];
    for (int i = threadIdx.x; i < NR * DD; i += 256) Lw[i] = W0[i];
    __syncthreads();
    int lane = threadIdx.x & 63;
    int wid = __builtin_amdgcn_readfirstlane(threadIdx.x >> 6);
    int n = blockIdx.x * 4 + wid;
    if (n >= NN) return;
    int r0 = dstoff[n], r1 = dstoff[n + 1];
    float deg = (float)(r1 - r0);
    float acc = b0[lane] + deg * L0[lane];
    for (int row = r0; row < r1; ++row) {
        unsigned v = msg0[row];
        acc += (float)(v & 0xffffu) * Lw[(v >> 16) * DD + lane];
    }
    acc = fmaxf(acc, 0.f);
    float other = __shfl_xor(acc, 1);
    if ((lane & 1) == 0) hpk0[n * 32 + (lane >> 1)] = pack2(acc, other);
}

// ---------------- fallback layer 0 ----------------
__global__ __launch_bounds__(256) void ktpass(const int* __restrict__ src, const int* __restrict__ dst,
                                              const int* __restrict__ et, const int* __restrict__ degi,
                                              float* __restrict__ T) {
    int e = blockIdx.x * 256 + threadIdx.x;
    if (e < NE) unsafeAtomicAdd(&T[dst[e] * NR + et[e]], (float)degi[src[e]]);
}

__global__ __launch_bounds__(256) void kf0(const float* __restrict__ T, const float* __restrict__ W0,
                                           const float* __restrict__ L0, const float* __restrict__ b0,
                                           const int* __restrict__ degi, unsigned* __restrict__ hpk0) {
    int lane = threadIdx.x & 63;
    int wid = __builtin_amdgcn_readfirstlane(threadIdx.x >> 6);
    int n = blockIdx.x * 4 + wid;
    if (n >= NN) return;
    float w0r[NR];
#pragma unroll
    for (int r = 0; r < NR; ++r) w0r[r] = W0[r * DD + lane];
    float acc = b0[lane] + (float)degi[n] * L0[lane];
    const float* Trow = T + n * NR;
#pragma unroll
    for (int r = 0; r < NR; ++r) acc += Trow[r] * w0r[r];
    acc = fmaxf(acc, 0.f);
    float other = __shfl_xor(acc, 1);
    if ((lane & 1) == 0) hpk0[n * 32 + (lane >> 1)] = pack2(acc, other);
}

// ---------------- MFMA message pass ----------------
template <bool STORE>
__global__ __launch_bounds__(256) void kmsgm(const unsigned short* __restrict__ sdp,
                                             const unsigned short* __restrict__ dsp,
                                             const int* __restrict__ perm,
                                             const int* __restrict__ batchptr, const unsigned* __restrict__ hpk,
                                             const unsigned* __restrict__ wpk, unsigned* __restrict__ out) {
    const int lane = threadIdx.x & 63;
    int wid = __builtin_amdgcn_readfirstlane(threadIdx.x >> 6);
    int gw = blockIdx.x * 4 + wid;
    const int nwaves = gridDim.x * 4;
    const int totB = batchptr[NR];
    int chunk = (totB + nwaves - 1) / nwaves;
    int b0 = gw * chunk;
    int b1 = min(b0 + chunk, totB);
    if (b0 >= b1) return;

    int r = 0;
    while (batchptr[r + 1] <= b0) ++r;

    hf8 Bf[8];
    auto loadB = [&](int rr) {
        const u32x4* wq = (const u32x4*)wpk;
#pragma unroll
        for (int f = 0; f < 8; ++f) Bf[f] = as_hf8(wq[(rr * 8 + f) * 64 + lane]);
    };
    loadB(r);
    int rend = batchptr[r + 1];

    const int qk = lane >> 4;       // 0..3 k-group / row-group
    const int lm = lane & 15;       // edge-row (A) / col-pair (C)

    for (int b = b0; b < b1; ++b) {
        while (b >= rend) {
            ++r;
            rend = batchptr[r + 1];
            if (b < rend) loadB(r);
        }
        int base = b << 4;
        int s = (int)sdp[base + lm];
        const unsigned* hr = hpk + (size_t)s * 32;
        hf8 a0 = as_hf8(*(const u32x4*)(hr + (qk << 2)));          // k in [0,32)
        hf8 a1 = as_hf8(*(const u32x4*)(hr + 16 + (qk << 2)));     // k in [32,64)
        i32x4 d4;
        if constexpr (STORE) {
            d4 = *(const i32x4*)(perm + base + (qk << 2));
        } else {
#pragma unroll
            for (int j = 0; j < 4; ++j) d4[j] = (int)dsp[base + (qk << 2) + j];
        }

        f32x4 acc0 = {0.f, 0.f, 0.f, 0.f};
        f32x4 acc1 = {0.f, 0.f, 0.f, 0.f};
        f32x4 acc2 = {0.f, 0.f, 0.f, 0.f};
        f32x4 acc3 = {0.f, 0.f, 0.f, 0.f};
        acc0 = __builtin_amdgcn_mfma_f32_16x16x32_f16(a0, Bf[0], acc0, 0, 0, 0);
        acc1 = __builtin_amdgcn_mfma_f32_16x16x32_f16(a0, Bf[1], acc1, 0, 0, 0);
        acc2 = __builtin_amdgcn_mfma_f32_16x16x32_f16(a0, Bf[2], acc2, 0, 0, 0);
        acc3 = __builtin_amdgcn_mfma_f32_16x16x32_f16(a0, Bf[3], acc3, 0, 0, 0);
        acc0 = __builtin_amdgcn_mfma_f32_16x16x32_f16(a1, Bf[4], acc0, 0, 0, 0);
        acc1 = __builtin_amdgcn_mfma_f32_16x16x32_f16(a1, Bf[5], acc1, 0, 0, 0);
        acc2 = __builtin_amdgcn_mfma_f32_16x16x32_f16(a1, Bf[6], acc2, 0, 0, 0);
        acc3 = __builtin_amdgcn_mfma_f32_16x16x32_f16(a1, Bf[7], acc3, 0, 0, 0);

#pragma unroll
        for (int j = 0; j < 4; ++j) {
            if constexpr (STORE) {
                unsigned pk0 = pack2(acc0[j], acc1[j]);
                unsigned pk1 = pack2(acc2[j], acc3[j]);
                unsigned long long v = ((unsigned long long)pk1 << 32) | pk0;
                *(unsigned long long*)(out + (size_t)d4[j] * 32 + 2 * lm) = v;
            } else {
                unsigned* ag = out + (size_t)d4[j] * 32 + lm;
                pkAtomicAdd(ag, acc0[j], acc1[j]);
                pkAtomicAdd(ag + 16, acc2[j], acc3[j]);
            }
        }
    }
}

// ---------------- finalize ----------------
// MSGMODE gather: lane = (ro8 = lane>>3 rows, q = lane&7 quads); 16B dwordx4 loads, 8 rows/iter.
// Row dword D: even -> cols (D, D+1); odd -> cols (31+D, 32+D).
template <bool ACT, bool WRITE_EMB, bool MSGMODE>
__global__ __launch_bounds__(256) void kfin(const unsigned* __restrict__ agm, const int* __restrict__ dstoff,
                                            const unsigned* __restrict__ hpk_in, const float* __restrict__ L,
                                            const float* __restrict__ bvec, unsigned* __restrict__ hpk_out,
                                            float* __restrict__ embp, const float* __restrict__ nuc,
                                            const float* __restrict__ gatew, const float* __restrict__ gateb,
                                            float* __restrict__ gate) {
    __shared__ unsigned Lp[32 * 64];
    for (int i = threadIdx.x; i < 2048; i += 256) {
        int kp = i >> 6, o = i & 63;
        Lp[i] = pack2(L[(2 * kp) * DD + o], L[(2 * kp + 1) * DD + o]);
    }
    __syncthreads();
    int lane = threadIdx.x & 63;
    int wid = __builtin_amdgcn_readfirstlane(threadIdx.x >> 6);
    int n = blockIdx.x * 4 + wid;
    if (n >= NN) return;
    float acc = bvec[lane];
    if constexpr (MSGMODE) {
        const int q = lane & 7;      // quad index: dwords 4q..4q+3
        const int ro8 = lane >> 3;   // row offset 0..7
        int r0 = dstoff[n], r1 = dstoff[n + 1];
        float m0 = 0.f, m1 = 0.f, m2 = 0.f, m3 = 0.f;
        float m4 = 0.f, m5 = 0.f, m6 = 0.f, m7 = 0.f;
        for (int row = r0; row < r1; row += 8) {
            int rr = row + ro8;
            u32x4 v = {0u, 0u, 0u, 0u};
            if (rr < r1) v = *(const u32x4*)(agm + (size_t)rr * 32 + 4 * q);
            m0 += half_at(v[0], 0); m1 += half_at(v[0], 1);   // D=4q   even: cols 4q, 4q+1
            m2 += half_at(v[1], 0); m3 += half_at(v[1], 1);   // D=4q+1 odd : cols 32+4q, 33+4q
            m4 += half_at(v[2], 0); m5 += half_at(v[2], 1);   // D=4q+2 even: cols 4q+2, 4q+3
            m6 += half_at(v[3], 0); m7 += half_at(v[3], 1);   // D=4q+3 odd : cols 34+4q, 35+4q
        }
        // reduce over row axis (lane bits 3,4,5)
        m0 += __shfl_xor(m0, 8); m0 += __shfl_xor(m0, 16); m0 += __shfl_xor(m0, 32);
        m1 += __shfl_xor(m1, 8); m1 += __shfl_xor(m1, 16); m1 += __shfl_xor(m1, 32);
        m2 += __shfl_xor(m2, 8); m2 += __shfl_xor(m2, 16); m2 += __shfl_xor(m2, 32);
        m3 += __shfl_xor(m3, 8); m3 += __shfl_xor(m3, 16); m3 += __shfl_xor(m3, 32);
        m4 += __shfl_xor(m4, 8); m4 += __shfl_xor(m4, 16); m4 += __shfl_xor(m4, 32);
        m5 += __shfl_xor(m5, 8); m5 += __shfl_xor(m5, 16); m5 += __shfl_xor(m5, 32);
        m6 += __shfl_xor(m6, 8); m6 += __shfl_xor(m6, 16); m6 += __shfl_xor(m6, 32);
        m7 += __shfl_xor(m7, 8); m7 += __shfl_xor(m7, 16); m7 += __shfl_xor(m7, 32);
        // redistribute: target col = lane. low cols: {m0,m1,m4,m5}[c&3] @ lane c>>2;
        // high cols (c=lane-32): {m2,m3,m6,m7}[c&3] @ lane c>>2.
        int qs = (lane & 31) >> 2;
        float lo0 = __shfl(m0, qs), lo1 = __shfl(m1, qs), lo2 = __shfl(m4, qs), lo3 = __shfl(m5, qs);
        float hi0 = __shfl(m2, qs), hi1 = __shfl(m3, qs), hi2 = __shfl(m6, qs), hi3 = __shfl(m7, qs);
        int rsel = lane & 3;
        float vlo = (rsel == 0) ? lo0 : (rsel == 1) ? lo1 : (rsel == 2) ? lo2 : lo3;
        float vhi = (rsel == 0) ? hi0 : (rsel == 1) ? hi1 : (rsel == 2) ? hi2 : hi3;
        acc += (lane >= 32) ? vhi : vlo;
    } else {
        acc += half_at(agm[(size_t)n * 32 + (lane >> 1)], lane & 1);
    }
    const unsigned* hr = hpk_in + n * 32;
    float a0 = 0.f, a1 = 0.f, a2 = 0.f, a3 = 0.f;
#pragma unroll
    for (int k4 = 0; k4 < 8; ++k4) {
        a0 = dot2f(hr[4 * k4 + 0], Lp[(4 * k4 + 0) * 64 + lane], a0);
        a1 = dot2f(hr[4 * k4 + 1], Lp[(4 * k4 + 1) * 64 + lane], a1);
        a2 = dot2f(hr[4 * k4 + 2], Lp[(4 * k4 + 2) * 64 + lane], a2);
        a3 = dot2f(hr[4 * k4 + 3], Lp[(4 * k4 + 3) * 64 + lane], a3);
    }
    acc += (a0 + a1) + (a2 + a3);
    if (ACT) acc = fmaxf(acc, 0.f);
    if constexpr (WRITE_EMB) {
        embp[(size_t)n * EMB + lane] = acc;
        float nv = nuc[n];
        if (lane == 0) embp[(size_t)n * EMB + 64] = nv;
        float v = acc * gatew[lane];
#pragma unroll
        for (int s = 32; s >= 1; s >>= 1) v += __shfl_xor(v, s);
        if (lane == 0) gate[n] = v + nv * gatew[64] + gateb[0];
    } else {
        float other = __shfl_xor(acc, 1);
        if ((lane & 1) == 0) hpk_out[n * 32 + (lane >> 1)] = pack2(acc, other);
    }
}

// ---------------- fused attention pooling + attributor MLP ----------------
__global__ __launch_bounds__(128) void kpoolmlp(const int* __restrict__ n2g, const float* __restrict__ gate,
                                                const float* __restrict__ emb, const float* __restrict__ A1,
                                                const float* __restrict__ ab1, const float* __restrict__ A2,
                                                const float* __restrict__ ab2, float* __restrict__ out) {
    __shared__ float red[128];
    __shared__ float c64[2];
    __shared__ float fv[EMB];
    __shared__ float h1[HID];
    int g = blockIdx.x;
    int t = threadIdx.x;
    int lo = lbound(n2g, g);
    int hi = lbound(n2g, g + 1);

    float m = -INFINITY;
    for (int i = lo + t; i < hi; i += 128) m = fmaxf(m, gate[i]);
    red[t] = m;
    __syncthreads();
    for (int s = 64; s > 0; s >>= 1) {
        if (t < s) red[t] = fmaxf(red[t], red[t + s]);
        __syncthreads();
    }
    m = red[0];
    __syncthreads();

    float sum = 0.f;
    for (int i = lo + t; i < hi; i += 128) sum += __expf(gate[i] - m);
    red[t] = sum;
    __syncthreads();
    for (int s = 64; s > 0; s >>= 1) {
        if (t < s) red[t] += red[t + s];
        __syncthreads();
    }
    float denom = red[0];
    __syncthreads();

    const int lane = t & 63;
    const int wv = t >> 6;
    float acc = 0.f, acc64 = 0.f;
    for (int i = lo + wv; i < hi; i += 2) {
        float wt = __expf(gate[i] - m);
        acc += wt * emb[(size_t)i * EMB + lane];
        if (lane == 0) acc64 += wt * emb[(size_t)i * EMB + 64];
    }
    red[t] = acc;
    if (lane == 0) c64[wv] = acc64;
    __syncthreads();
    if (t < 64) {
        float s = red[t] + red[64 + t];
        fv[t] = (hi > lo) ? s / denom : 0.f;
    } else if (t == 64) {
        float s = c64[0] + c64[1];
        fv[64] = (hi > lo) ? s / denom : 0.f;
    }
    __syncthreads();

    float a = ab1[t];
    for (int d = 0; d < EMB; ++d) a += fv[d] * A1[d * HID + t];
    h1[t] = fmaxf(a, 0.f);
    __syncthreads();
    for (int o = t; o < FP; o += HID) {
        float v = ab2[o];
        for (int k = 0; k < HID; ++k) v += h1[k] * A2[k * FP + o];
        out[(size_t)g * FP + o] = 1.f / (1.f + __expf(-v));
    }
}

extern "C" void kernel_launch(void* const* d_in, const int* in_sizes, int n_in,
                              void* d_out, int out_size, void* d_ws, size_t ws_size,
                              hipStream_t stream) {
    const int* src = (const int*)d_in[0];
    const int* dst = (const int*)d_in[1];
    const int* et = (const int*)d_in[2];
    const int* n2g = (const int*)d_in[3];
    const float* nuc = (const float*)d_in[4];
    const float* W0 = (const float*)d_in[5];
    const float* b0 = (const float*)d_in[6];
    const float* L0 = (const float*)d_in[7];
    const float* W1 = (const float*)d_in[8];
    const float* b1 = (const float*)d_in[9];
    const float* L1 = (const float*)d_in[10];
    const float* W2 = (const float*)d_in[11];
    const float* b2 = (const float*)d_in[12];
    const float* L2 = (const float*)d_in[13];
    const float* gatew = (const float*)d_in[14];
    const float* gateb = (const float*)d_in[15];
    const float* A1 = (const float*)d_in[16];
    const float* ab1 = (const float*)d_in[17];
    const float* A2 = (const float*)d_in[18];
    const float* ab2 = (const float*)d_in[19];
    (void)in_sizes; (void)n_in; (void)out_size;

    float* out0 = (float*)d_out;                      // [G,166]
    float* embp = (float*)d_out + (size_t)NG * FP;    // [N,65]

    char* w = (char*)d_ws;
    size_t off = 0;
    auto alloc = [&](size_t bytes) { size_t r = off; off = (off + bytes + 255) & ~(size_t)255; return r; };

    // zeroed span: degi + cnt19 (store path); + T (fallback)
    size_t o_degi = alloc(NN * 4);
    size_t o_cnt  = alloc(NR * 4);
    size_t zero_small = off;
    size_t o_T    = alloc((size_t)NN * NR * 4);
    size_t zero_big = off;
    size_t o_hpk0 = alloc((size_t)(NN + 1) * 32 * 4);
    size_t o_hpk1 = alloc((size_t)(NN + 1) * 32 * 4);
    size_t o_pb   = alloc((NR + 1) * 4);
    size_t o_cur19= alloc(NR * 4);
    size_t o_bp   = alloc((NR + 1) * 4);
    size_t o_sdp  = alloc((size_t)NEP * 2);
    size_t o_dsp  = alloc((size_t)NEP * 2);
    size_t o_perm = alloc((size_t)NEP * 4);
    size_t o_msg0 = alloc((size_t)NMSG * 4);
    size_t o_doff = alloc((size_t)(NN + 1) * 4);
    size_t o_cur  = alloc((size_t)(NN + 1) * 4);
    size_t o_part = alloc((size_t)SCB5 * 4);
    size_t o_wpk1 = alloc((size_t)NR * 8 * 64 * 16);
    size_t o_wpk2 = alloc((size_t)NR * 8 * 64 * 16);
    size_t o_gate = alloc(NN * 4);
    size_t o_msg  = off;  // tail region: msg (store path) or aggh (fallback)
    size_t need_store = o_msg + (size_t)NMSG * 128;
    bool use_store = ws_size >= need_store;

    int* degi = (int*)(w + o_degi);
    int* cnt19 = (int*)(w + o_cnt);
    float* T = (float*)(w + o_T);
    unsigned* hpk0 = (unsigned*)(w + o_hpk0);
    unsigned* hpk1 = (unsigned*)(w + o_hpk1);
    int* pbase = (int*)(w + o_pb);
    int* cur19 = (int*)(w + o_cur19);
    int* batchptr = (int*)(w + o_bp);
    unsigned short* sdp = (unsigned short*)(w + o_sdp);
    unsigned short* dsp = (unsigned short*)(w + o_dsp);
    int* perm = (int*)(w + o_perm);
    unsigned* msg0 = (unsigned*)(w + o_msg0);
    int* dstoff = (int*)(w + o_doff);
    int* cur = (int*)(w + o_cur);
    int* part = (int*)(w + o_part);
    unsigned* wpk1 = (unsigned*)(w + o_wpk1);
    unsigned* wpk2 = (unsigned*)(w + o_wpk2);
    float* gate = (float*)(w + o_gate);
    unsigned* msg = (unsigned*)(w + o_msg);   // also aggh in fallback

    const int EB  = (NE + 255) / 256;        // 3125
    const int NW  = (NN + 3) / 4;            // 12500

    hipMemsetAsync(w, 0, use_store ? zero_small : zero_big, stream);

    // D1: etype hist (block-combined flush) || degree hist
    kd1<<<ET5 + EB5, 512, 0, stream>>>(dst, et, degi, cnt19);
    // D2: scanA || scan19+pad(+perm dump) || W pack
    kd2<<<SCB5 + 1 + WPB512, 512, 0, stream>>>(degi, part, cnt19, pbase, cur19, batchptr,
                                               hpk0, hpk1, sdp, dsp, perm, W1, W2, wpk1, wpk2);
    // D3: scanBC (dstoff + cur)
    kd3<<<SCB5, 512, 0, stream>>>(degi, part, dstoff, cur);
    // D4: fused scatter + CSR slot + perm + msg0
    kd4<<<EB5, 512, 0, stream>>>(src, dst, et, cur19, degi, cur, sdp,
                                 use_store ? nullptr : dsp, perm, msg0);

    if (use_store) {
        kf0m<<<NW, 256, 0, stream>>>(msg0, dstoff, W0, L0, b0, hpk0);

        // layer 1
        kmsgm<true><<<1024, 256, 0, stream>>>(sdp, nullptr, perm, batchptr, hpk0, wpk1, msg);
        kfin<true, false, true><<<NW, 256, 0, stream>>>(msg, dstoff, hpk0, L1, b1, hpk1,
                                                        nullptr, nullptr, nullptr, nullptr, nullptr);
        // layer 2
        kmsgm<true><<<1024, 256, 0, stream>>>(sdp, nullptr, perm, batchptr, hpk1, wpk2, msg);
        kfin<false, true, true><<<NW, 256, 0, stream>>>(msg, dstoff, hpk1, L2, b2, nullptr,
                                                        embp, nuc, gatew, gateb, gate);
    } else {
        // fallback: pk-f16 atomic aggregation
        ktpass<<<EB, 256, 0, stream>>>(src, dst, et, degi, T);
        kf0<<<NW, 256, 0, stream>>>(T, W0, L0, b0, degi, hpk0);
        hipMemsetAsync(msg, 0, (size_t)NN * 32 * 4, stream);
        kmsgm<false><<<1024, 256, 0, stream>>>(sdp, dsp, nullptr, batchptr, hpk0, wpk1, msg);
        kfin<true, false, false><<<NW, 256, 0, stream>>>(msg, nullptr, hpk0, L1, b1, hpk1,
                                                         nullptr, nullptr, nullptr, nullptr, nullptr);
        hipMemsetAsync(msg, 0, (size_t)NN * 32 * 4, stream);
        kmsgm<false><<<1024, 256, 0, stream>>>(sdp, dsp, nullptr, batchptr, hpk1, wpk2, msg);
        kfin<false, true, false><<<NW, 256, 0, stream>>>(msg, nullptr, hpk1, L2, b2, nullptr,
                                                         embp, nuc, gatew, gateb, gate);
    }

    // fused pooling + MLP
    kpoolmlp<<<NG, 128, 0, stream>>>(n2g, gate, embp, A1, ab1, A2, ab2, out0);
}

// Round 21
// 298.619 us; speedup vs baseline: 1.0351x; 1.0351x over previous
//
#include <hip/hip_runtime.h>
#include <cstdint>

// Problem constants (fixed by the reference)
static constexpr int NN = 50000;   // nodes
static constexpr int NE = 800000;  // edges
static constexpr int NG = 512;     // graphs
static constexpr int NR = 19;      // relations
static constexpr int DD = 64;      // hidden dim
static constexpr int EMB = 65;
static constexpr int HID = 128;
static constexpr int FP = 166;
static constexpr int NEP = NE + NR * 16;   // padded edge capacity (etype bins)
static constexpr int NMSG = NE + 304;      // msg rows incl. pad dump zone
static constexpr int SCB5 = (NN + 511) / 512;      // 98
static constexpr int EB5  = (NE + 511) / 512;      // 1563
static constexpr int ET5  = (NE + 4095) / 4096;    // 196
static constexpr int WPB512 = (2 * NR * 8 * 64 + 511) / 512;  // 38

typedef __fp16 h2 __attribute__((ext_vector_type(2)));
typedef _Float16 F16x2 __attribute__((ext_vector_type(2)));
typedef _Float16 hf8 __attribute__((ext_vector_type(8)));
typedef float f32x4 __attribute__((ext_vector_type(4)));
typedef unsigned u32x4 __attribute__((ext_vector_type(4)));
typedef int i32x4 __attribute__((ext_vector_type(4)));

union U4H8 { u32x4 u; hf8 h; };

__device__ __forceinline__ hf8 as_hf8(u32x4 u) { U4H8 c; c.u = u; return c.h; }

__device__ __forceinline__ float dot2f(unsigned a, unsigned b, float c) {
    union { unsigned u; h2 h; } ua, ub;
    ua.u = a; ub.u = b;
    return __builtin_amdgcn_fdot2(ua.h, ub.h, c, false);
}

__device__ __forceinline__ unsigned pack2(float a, float b) {
    union { h2 h; unsigned u; } r;
    r.h = __builtin_amdgcn_cvt_pkrtz(a, b);
    return r.u;
}

__device__ __forceinline__ void pkAtomicAdd(unsigned* addr, float lo, float hi) {
    unsigned u = pack2(lo, hi);
#if __has_builtin(__builtin_amdgcn_global_atomic_fadd_v2f16)
    union { unsigned u; F16x2 h; } c; c.u = u;
    __builtin_amdgcn_global_atomic_fadd_v2f16((F16x2*)addr, c.h);
#else
    asm volatile("global_atomic_pk_add_f16 %0, %1, off" :: "v"(addr), "v"(u) : "memory");
#endif
}

__device__ __forceinline__ float half_at(unsigned v, int idx) {
    union { unsigned u; h2 h; } c; c.u = v;
    return (float)c.h[idx];
}

// first index in sorted n2g with n2g[idx] >= key
__device__ __forceinline__ int lbound(const int* __restrict__ a, int key) {
    int lo = 0, hi = NN;
    while (lo < hi) {
        int mid = (lo + hi) >> 1;
        if (a[mid] < key) lo = mid + 1; else hi = mid;
    }
    return lo;
}

// ====== D1: ketcnt (blocks [0,ET5), block-combined flush) || degree hist (1 edge/thread) =======
__global__ __launch_bounds__(512) void kd1(const int* __restrict__ dst, const int* __restrict__ et,
                                           int* __restrict__ degi, int* __restrict__ cnt19) {
    const int b = blockIdx.x;
    const int t = threadIdx.x;
    if (b < ET5) {
        __shared__ int lcnt[8][NR];
        const int lane = t & 63;
        const int wid = t >> 6;   // 0..7
        const int wbase = (b * 8 + wid) * 512;
        int cnt = 0;
#pragma unroll
        for (int i = 0; i < 8; ++i) {
            int e = wbase + i * 64 + lane;
            int myet = (e < NE) ? et[e] : -1;
#pragma unroll
            for (int r = 0; r < NR; ++r) {
                unsigned long long bm = __ballot(myet == r);
                if (lane == r) cnt += (int)__popcll(bm);
            }
        }
        if (lane < NR) lcnt[wid][lane] = cnt;
        __syncthreads();
        if (t < NR) {
            int s = 0;
#pragma unroll
            for (int wv = 0; wv < 8; ++wv) s += lcnt[wv][t];
            if (s) atomicAdd(&cnt19[t], s);
        }
    } else {
        int e = (b - ET5) * 512 + t;
        if (e < NE) atomicAdd(&degi[dst[e]], 1);
    }
}

// ===== D2: kscanA [0,SCB5) || scan19+pad (b==SCB5, pads get perm=NE dump) || Wpack =============
__global__ __launch_bounds__(512) void kd2(const int* __restrict__ degi, int* __restrict__ part,
                                           const int* __restrict__ cnt19, int* __restrict__ pbase,
                                           int* __restrict__ cur19, int* __restrict__ batchptr,
                                           unsigned* __restrict__ hpk0, unsigned* __restrict__ hpk1,
                                           unsigned* __restrict__ sdp, int* __restrict__ perm,
                                           const float* __restrict__ W1, const float* __restrict__ W2,
                                           unsigned* __restrict__ wpk1, unsigned* __restrict__ wpk2) {
    const int b = blockIdx.x;
    const int t = threadIdx.x;
    if (b < SCB5) {
        __shared__ int red[512];
        int idx = b * 512 + t;
        red[t] = (idx < NN) ? degi[idx] : 0;
        __syncthreads();
#pragma unroll
        for (int s = 256; s > 0; s >>= 1) {
            if (t < s) red[t] += red[t + s];
            __syncthreads();
        }
        if (t == 0) part[b] = red[0];
    } else if (b == SCB5) {
        __shared__ int spb[NR + 1];
        if (t == 0) {
            int run = 0;
            for (int r = 0; r < NR; ++r) {
                spb[r] = run; pbase[r] = run; cur19[r] = run; batchptr[r] = run >> 4;
                run += (cnt19[r] + 15) & ~15;
            }
            spb[NR] = run; pbase[NR] = run; batchptr[NR] = run >> 4;
        }
        if (t < 32) hpk0[(size_t)NN * 32 + t] = 0;
        else if (t < 64) hpk1[(size_t)NN * 32 + (t - 32)] = 0;
        __syncthreads();
        int r = t >> 4, i = t & 15;
        if (r < NR) {
            int cnt = cnt19[r];
            int tail = spb[r + 1] - spb[r] - cnt;
            if (i < tail) {
                int pos = spb[r] + cnt + i;
                sdp[pos] = (unsigned)NN | ((unsigned)NN << 16);  // src=NN zero h row
                perm[pos] = NE;                                   // dump msg row (never read)
            }
        }
    } else {
        int tt = (b - SCB5 - 1) * 512 + t;
        if (tt >= 2 * NR * 8 * 64) return;
        int which = tt >= NR * 8 * 64;
        int t2 = tt - which * NR * 8 * 64;
        const float* W = which ? W2 : W1;
        unsigned* wpk = which ? wpk2 : wpk1;
        int lane = t2 & 63;
        int f = (t2 >> 6) & 7;
        int r = t2 >> 9;
        int kh = f >> 2, ct = f & 3;
        int kbase = kh * 32 + (lane >> 4) * 8;
        int col = (ct >> 1) * 32 + 2 * (lane & 15) + (ct & 1);
        const float* wr = W + (size_t)r * DD * DD;
        u32x4 out;
#pragma unroll
        for (int p = 0; p < 4; ++p)
            out[p] = pack2(wr[(kbase + 2 * p) * DD + col], wr[(kbase + 2 * p + 1) * DD + col]);
        *((u32x4*)wpk + t2) = out;
    }
}

// ================= D3: kscanBC alone (98 blocks) ==============================================
__global__ __launch_bounds__(512) void kd3(const int* __restrict__ degi, const int* __restrict__ part,
                                           int* __restrict__ dstoff, int* __restrict__ cur) {
    __shared__ int sp[512];
    __shared__ int s[512];
    const int b = blockIdx.x;
    const int t = threadIdx.x;
    sp[t] = (t < SCB5) ? part[t] : 0;
    int idx = b * 512 + t;
    int v = (idx < NN) ? degi[idx] : 0;
    s[t] = v;
    __syncthreads();
#pragma unroll
    for (int d = 1; d < 512; d <<= 1) {
        int x1 = (t >= d) ? sp[t - d] : 0;
        int x2 = (t >= d) ? s[t - d] : 0;
        __syncthreads();
        sp[t] += x1;
        s[t] += x2;
        __syncthreads();
    }
    int boff = (b == 0) ? 0 : sp[b - 1];
    int excl = boff + ((t == 0) ? 0 : s[t - 1]);
    if (idx < NN) { dstoff[idx] = excl; cur[idx] = excl; }
    if (idx == NN - 1) { dstoff[NN] = NE; cur[NN] = NE; }
}

// ==== D4: fused counting-sort scatter + CSR slot atomic + perm + layer-0 msg0 ==================
__global__ __launch_bounds__(512) void kd4(const int* __restrict__ src, const int* __restrict__ dst,
                                           const int* __restrict__ et, int* __restrict__ cur19,
                                           const int* __restrict__ degi, int* __restrict__ cur,
                                           unsigned* __restrict__ sdp, int* __restrict__ perm,
                                           unsigned* __restrict__ msg0) {
    __shared__ int wcnt[8][NR];
    __shared__ int lb[NR];
    __shared__ int woff[8][NR];
    const int b = blockIdx.x;
    const int t = threadIdx.x;
    const int lane = t & 63;
    const int wid = t >> 6;   // 0..7
    int e = b * 512 + t;
    int myet = -1, d = 0, sv = 0;
    if (e < NE) { myet = et[e]; d = dst[e]; sv = src[e]; }
    const unsigned long long below = (lane == 63) ? ~0ull >> 1 : ((1ull << lane) - 1);
    int myrank = 0, cnt_r = 0;
#pragma unroll
    for (int r = 0; r < NR; ++r) {
        unsigned long long m = __ballot(myet == r);
        if (myet == r) myrank = (int)__popcll(m & below);
        if (lane == r) cnt_r = (int)__popcll(m);
    }
    if (lane < NR) wcnt[wid][lane] = cnt_r;
    __syncthreads();
    if (t < NR) {
        int run = 0, c[8];
#pragma unroll
        for (int wv = 0; wv < 8; ++wv) { c[wv] = wcnt[wv][t]; }
#pragma unroll
        for (int wv = 0; wv < 8; ++wv) { woff[wv][t] = run; run += c[wv]; }
        lb[t] = run ? atomicAdd(&cur19[t], run) : 0;
    }
    __syncthreads();
    if (e < NE) {
        int pos = lb[myet] + woff[wid][myet] + myrank;
        sdp[pos] = (unsigned)sv | ((unsigned)d << 16);
        int deg = degi[sv];
        int slot = atomicAdd(&cur[d], 1);
        perm[pos] = slot;
        msg0[slot] = ((unsigned)myet << 16) | (unsigned)deg;
    }
}

// ---------------- layer 0 (store path): h0 = relu(sum_rows deg*W0[et] + deg*L0 + b0) -----------
__global__ __launch_bounds__(256) void kf0m(const unsigned* __restrict__ msg0, const int* __restrict__ dstoff,
                                            const float* __restrict__ W0, const float* __restrict__ L0,
                                            const float* __restrict__ b0, unsigned* __restrict__ hpk0) {
    __shared__ float Lw[NR * DD];
    for (int i = threadIdx.x; i < NR * DD; i += 256) Lw[i] = W0[i];
    __syncthreads();
    int lane = threadIdx.x & 63;
    int wid = __builtin_amdgcn_readfirstlane(threadIdx.x >> 6);
    int n = blockIdx.x * 4 + wid;
    if (n >= NN) return;
    int r0 = dstoff[n], r1 = dstoff[n + 1];
    float deg = (float)(r1 - r0);
    float acc = b0[lane] + deg * L0[lane];
    for (int row = r0; row < r1; ++row) {
        unsigned v = msg0[row];
        acc += (float)(v & 0xffffu) * Lw[(v >> 16) * DD + lane];
    }
    acc = fmaxf(acc, 0.f);
    float other = __shfl_xor(acc, 1);
    if ((lane & 1) == 0) hpk0[n * 32 + (lane >> 1)] = pack2(acc, other);
}

// ---------------- fallback layer 0 ----------------
__global__ __launch_bounds__(256) void ktpass(const int* __restrict__ src, const int* __restrict__ dst,
                                              const int* __restrict__ et, const int* __restrict__ degi,
                                              float* __restrict__ T) {
    int e = blockIdx.x * 256 + threadIdx.x;
    if (e < NE) unsafeAtomicAdd(&T[dst[e] * NR + et[e]], (float)degi[src[e]]);
}

__global__ __launch_bounds__(256) void kf0(const float* __restrict__ T, const float* __restrict__ W0,
                                           const float* __restrict__ L0, const float* __restrict__ b0,
                                           const int* __restrict__ degi, unsigned* __restrict__ hpk0) {
    int lane = threadIdx.x & 63;
    int wid = __builtin_amdgcn_readfirstlane(threadIdx.x >> 6);
    int n = blockIdx.x * 4 + wid;
    if (n >= NN) return;
    float w0r[NR];
#pragma unroll
    for (int r = 0; r < NR; ++r) w0r[r] = W0[r * DD + lane];
    float acc = b0[lane] + (float)degi[n] * L0[lane];
    const float* Trow = T + n * NR;
#pragma unroll
    for (int r = 0; r < NR; ++r) acc += Trow[r] * w0r[r];
    acc = fmaxf(acc, 0.f);
    float other = __shfl_xor(acc, 1);
    if ((lane & 1) == 0) hpk0[n * 32 + (lane >> 1)] = pack2(acc, other);
}

// ---------------- MFMA message pass ----------------
template <bool STORE>
__global__ __launch_bounds__(256) void kmsgm(const unsigned* __restrict__ sdp, const int* __restrict__ perm,
                                             const int* __restrict__ batchptr, const unsigned* __restrict__ hpk,
                                             const unsigned* __restrict__ wpk, unsigned* __restrict__ out) {
    const int lane = threadIdx.x & 63;
    int wid = __builtin_amdgcn_readfirstlane(threadIdx.x >> 6);
    int gw = blockIdx.x * 4 + wid;
    const int nwaves = gridDim.x * 4;
    const int totB = batchptr[NR];
    int chunk = (totB + nwaves - 1) / nwaves;
    int b0 = gw * chunk;
    int b1 = min(b0 + chunk, totB);
    if (b0 >= b1) return;

    int r = 0;
    while (batchptr[r + 1] <= b0) ++r;

    hf8 Bf[8];
    auto loadB = [&](int rr) {
        const u32x4* wq = (const u32x4*)wpk;
#pragma unroll
        for (int f = 0; f < 8; ++f) Bf[f] = as_hf8(wq[(rr * 8 + f) * 64 + lane]);
    };
    loadB(r);
    int rend = batchptr[r + 1];

    const int qk = lane >> 4;       // 0..3 k-group / row-group
    const int lm = lane & 15;       // edge-row (A) / col-pair (C)

    for (int b = b0; b < b1; ++b) {
        while (b >= rend) {
            ++r;
            rend = batchptr[r + 1];
            if (b < rend) loadB(r);
        }
        int base = b << 4;
        int s = (int)(sdp[base + lm] & 0xffffu);
        const unsigned* hr = hpk + (size_t)s * 32;
        hf8 a0 = as_hf8(*(const u32x4*)(hr + (qk << 2)));          // k in [0,32)
        hf8 a1 = as_hf8(*(const u32x4*)(hr + 16 + (qk << 2)));     // k in [32,64)
        i32x4 d4;
        if constexpr (STORE) {
            d4 = *(const i32x4*)(perm + base + (qk << 2));
        } else {
            u32x4 sd4 = *(const u32x4*)(sdp + base + (qk << 2));
#pragma unroll
            for (int j = 0; j < 4; ++j) d4[j] = (int)(sd4[j] >> 16);
        }

        f32x4 acc0 = {0.f, 0.f, 0.f, 0.f};
        f32x4 acc1 = {0.f, 0.f, 0.f, 0.f};
        f32x4 acc2 = {0.f, 0.f, 0.f, 0.f};
        f32x4 acc3 = {0.f, 0.f, 0.f, 0.f};
        acc0 = __builtin_amdgcn_mfma_f32_16x16x32_f16(a0, Bf[0], acc0, 0, 0, 0);
        acc1 = __builtin_amdgcn_mfma_f32_16x16x32_f16(a0, Bf[1], acc1, 0, 0, 0);
        acc2 = __builtin_amdgcn_mfma_f32_16x16x32_f16(a0, Bf[2], acc2, 0, 0, 0);
        acc3 = __builtin_amdgcn_mfma_f32_16x16x32_f16(a0, Bf[3], acc3, 0, 0, 0);
        acc0 = __builtin_amdgcn_mfma_f32_16x16x32_f16(a1, Bf[4], acc0, 0, 0, 0);
        acc1 = __builtin_amdgcn_mfma_f32_16x16x32_f16(a1, Bf[5], acc1, 0, 0, 0);
        acc2 = __builtin_amdgcn_mfma_f32_16x16x32_f16(a1, Bf[6], acc2, 0, 0, 0);
        acc3 = __builtin_amdgcn_mfma_f32_16x16x32_f16(a1, Bf[7], acc3, 0, 0, 0);

#pragma unroll
        for (int j = 0; j < 4; ++j) {
            if constexpr (STORE) {
                unsigned pk0 = pack2(acc0[j], acc1[j]);
                unsigned pk1 = pack2(acc2[j], acc3[j]);
                unsigned long long v = ((unsigned long long)pk1 << 32) | pk0;
                *(unsigned long long*)(out + (size_t)d4[j] * 32 + 2 * lm) = v;
            } else {
                unsigned* ag = out + (size_t)d4[j] * 32 + lm;
                pkAtomicAdd(ag, acc0[j], acc1[j]);
                pkAtomicAdd(ag + 16, acc2[j], acc3[j]);
            }
        }
    }
}

// ---------------- finalize ----------------
template <bool ACT, bool WRITE_EMB, bool MSGMODE>
__global__ __launch_bounds__(256) void kfin(const unsigned* __restrict__ agm, const int* __restrict__ dstoff,
                                            const unsigned* __restrict__ hpk_in, const float* __restrict__ L,
                                            const float* __restrict__ bvec, unsigned* __restrict__ hpk_out,
                                            float* __restrict__ embp, const float* __restrict__ nuc,
                                            const float* __restrict__ gatew, const float* __restrict__ gateb,
                                            float* __restrict__ gate) {
    __shared__ unsigned Lp[32 * 64];
    for (int i = threadIdx.x; i < 2048; i += 256) {
        int kp = i >> 6, o = i & 63;
        Lp[i] = pack2(L[(2 * kp) * DD + o], L[(2 * kp + 1) * DD + o]);
    }
    __syncthreads();
    int lane = threadIdx.x & 63;
    int wid = __builtin_amdgcn_readfirstlane(threadIdx.x >> 6);
    int n = blockIdx.x * 4 + wid;
    if (n >= NN) return;
    float acc = bvec[lane];
    if constexpr (MSGMODE) {
        const int dwp = lane & 15;
        const int ro = lane >> 4;
        int r0 = dstoff[n], r1 = dstoff[n + 1];
        float m0a = 0.f, m1a = 0.f, m2a = 0.f, m3a = 0.f;
        for (int row = r0; row < r1; row += 4) {
            int rr = row + ro;
            unsigned long long v = 0;
            if (rr < r1) v = *(const unsigned long long*)(agm + (size_t)rr * 32 + 2 * dwp);
            unsigned vlo = (unsigned)v, vhi = (unsigned)(v >> 32);
            m0a += half_at(vlo, 0); m1a += half_at(vlo, 1);
            m2a += half_at(vhi, 0); m3a += half_at(vhi, 1);
        }
        m0a += __shfl_xor(m0a, 16); m0a += __shfl_xor(m0a, 32);
        m1a += __shfl_xor(m1a, 16); m1a += __shfl_xor(m1a, 32);
        m2a += __shfl_xor(m2a, 16); m2a += __shfl_xor(m2a, 32);
        m3a += __shfl_xor(m3a, 16); m3a += __shfl_xor(m3a, 32);
        int dp = (lane & 31) >> 1;
        float s0 = __shfl(m0a, dp), s1 = __shfl(m1a, dp);
        float s2 = __shfl(m2a, dp), s3 = __shfl(m3a, dp);
        float sel_lo = (lane & 1) ? s1 : s0;
        float sel_hi = (lane & 1) ? s3 : s2;
        acc += (lane >= 32) ? sel_hi : sel_lo;
    } else {
        acc += half_at(agm[(size_t)n * 32 + (lane >> 1)], lane & 1);
    }
    const unsigned* hr = hpk_in + n * 32;
    float a0 = 0.f, a1 = 0.f, a2 = 0.f, a3 = 0.f;
#pragma unroll
    for (int k4 = 0; k4 < 8; ++k4) {
        a0 = dot2f(hr[4 * k4 + 0], Lp[(4 * k4 + 0) * 64 + lane], a0);
        a1 = dot2f(hr[4 * k4 + 1], Lp[(4 * k4 + 1) * 64 + lane], a1);
        a2 = dot2f(hr[4 * k4 + 2], Lp[(4 * k4 + 2) * 64 + lane], a2);
        a3 = dot2f(hr[4 * k4 + 3], Lp[(4 * k4 + 3) * 64 + lane], a3);
    }
    acc += (a0 + a1) + (a2 + a3);
    if (ACT) acc = fmaxf(acc, 0.f);
    if constexpr (WRITE_EMB) {
        embp[(size_t)n * EMB + lane] = acc;
        float nv = nuc[n];
        if (lane == 0) embp[(size_t)n * EMB + 64] = nv;
        float v = acc * gatew[lane];
#pragma unroll
        for (int s = 32; s >= 1; s >>= 1) v += __shfl_xor(v, s);
        if (lane == 0) gate[n] = v + nv * gatew[64] + gateb[0];
    } else {
        float other = __shfl_xor(acc, 1);
        if ((lane & 1) == 0) hpk_out[n * 32 + (lane >> 1)] = pack2(acc, other);
    }
}

// ---------------- fused attention pooling + attributor MLP ----------------
__global__ __launch_bounds__(128) void kpoolmlp(const int* __restrict__ n2g, const float* __restrict__ gate,
                                                const float* __restrict__ emb, const float* __restrict__ A1,
                                                const float* __restrict__ ab1, const float* __restrict__ A2,
                                                const float* __restrict__ ab2, float* __restrict__ out) {
    __shared__ float red[128];
    __shared__ float c64[2];
    __shared__ float fv[EMB];
    __shared__ float h1[HID];
    int g = blockIdx.x;
    int t = threadIdx.x;
    int lo = lbound(n2g, g);
    int hi = lbound(n2g, g + 1);

    float m = -INFINITY;
    for (int i = lo + t; i < hi; i += 128) m = fmaxf(m, gate[i]);
    red[t] = m;
    __syncthreads();
    for (int s = 64; s > 0; s >>= 1) {
        if (t < s) red[t] = fmaxf(red[t], red[t + s]);
        __syncthreads();
    }
    m = red[0];
    __syncthreads();

    float sum = 0.f;
    for (int i = lo + t; i < hi; i += 128) sum += __expf(gate[i] - m);
    red[t] = sum;
    __syncthreads();
    for (int s = 64; s > 0; s >>= 1) {
        if (t < s) red[t] += red[t + s];
        __syncthreads();
    }
    float denom = red[0];
    __syncthreads();

    const int lane = t & 63;
    const int wv = t >> 6;
    float acc = 0.f, acc64 = 0.f;
    for (int i = lo + wv; i < hi; i += 2) {
        float wt = __expf(gate[i] - m);
        acc += wt * emb[(size_t)i * EMB + lane];
        if (lane == 0) acc64 += wt * emb[(size_t)i * EMB + 64];
    }
    red[t] = acc;
    if (lane == 0) c64[wv] = acc64;
    __syncthreads();
    if (t < 64) {
        float s = red[t] + red[64 + t];
        fv[t] = (hi > lo) ? s / denom : 0.f;
    } else if (t == 64) {
        float s = c64[0] + c64[1];
        fv[64] = (hi > lo) ? s / denom : 0.f;
    }
    __syncthreads();

    float a = ab1[t];
    for (int d = 0; d < EMB; ++d) a += fv[d] * A1[d * HID + t];
    h1[t] = fmaxf(a, 0.f);
    __syncthreads();
    for (int o = t; o < FP; o += HID) {
        float v = ab2[o];
        for (int k = 0; k < HID; ++k) v += h1[k] * A2[k * FP + o];
        out[(size_t)g * FP + o] = 1.f / (1.f + __expf(-v));
    }
}

extern "C" void kernel_launch(void* const* d_in, const int* in_sizes, int n_in,
                              void* d_out, int out_size, void* d_ws, size_t ws_size,
                              hipStream_t stream) {
    const int* src = (const int*)d_in[0];
    const int* dst = (const int*)d_in[1];
    const int* et = (const int*)d_in[2];
    const int* n2g = (const int*)d_in[3];
    const float* nuc = (const float*)d_in[4];
    const float* W0 = (const float*)d_in[5];
    const float* b0 = (const float*)d_in[6];
    const float* L0 = (const float*)d_in[7];
    const float* W1 = (const float*)d_in[8];
    const float* b1 = (const float*)d_in[9];
    const float* L1 = (const float*)d_in[10];
    const float* W2 = (const float*)d_in[11];
    const float* b2 = (const float*)d_in[12];
    const float* L2 = (const float*)d_in[13];
    const float* gatew = (const float*)d_in[14];
    const float* gateb = (const float*)d_in[15];
    const float* A1 = (const float*)d_in[16];
    const float* ab1 = (const float*)d_in[17];
    const float* A2 = (const float*)d_in[18];
    const float* ab2 = (const float*)d_in[19];
    (void)in_sizes; (void)n_in; (void)out_size;

    float* out0 = (float*)d_out;                      // [G,166]
    float* embp = (float*)d_out + (size_t)NG * FP;    // [N,65]

    char* w = (char*)d_ws;
    size_t off = 0;
    auto alloc = [&](size_t bytes) { size_t r = off; off = (off + bytes + 255) & ~(size_t)255; return r; };

    // zeroed span: degi + cnt19 (store path); + T (fallback)
    size_t o_degi = alloc(NN * 4);
    size_t o_cnt  = alloc(NR * 4);
    size_t zero_small = off;
    size_t o_T    = alloc((size_t)NN * NR * 4);
    size_t zero_big = off;
    size_t o_hpk0 = alloc((size_t)(NN + 1) * 32 * 4);
    size_t o_hpk1 = alloc((size_t)(NN + 1) * 32 * 4);
    size_t o_pb   = alloc((NR + 1) * 4);
    size_t o_cur19= alloc(NR * 4);
    size_t o_bp   = alloc((NR + 1) * 4);
    size_t o_sdp  = alloc((size_t)NEP * 4);
    size_t o_perm = alloc((size_t)NEP * 4);
    size_t o_msg0 = alloc((size_t)NMSG * 4);
    size_t o_doff = alloc((size_t)(NN + 1) * 4);
    size_t o_cur  = alloc((size_t)(NN + 1) * 4);
    size_t o_part = alloc((size_t)SCB5 * 4);
    size_t o_wpk1 = alloc((size_t)NR * 8 * 64 * 16);
    size_t o_wpk2 = alloc((size_t)NR * 8 * 64 * 16);
    size_t o_gate = alloc(NN * 4);
    size_t o_msg  = off;  // tail region: msg (store path) or aggh (fallback)
    size_t need_store = o_msg + (size_t)NMSG * 128;
    bool use_store = ws_size >= need_store;

    int* degi = (int*)(w + o_degi);
    int* cnt19 = (int*)(w + o_cnt);
    float* T = (float*)(w + o_T);
    unsigned* hpk0 = (unsigned*)(w + o_hpk0);
    unsigned* hpk1 = (unsigned*)(w + o_hpk1);
    int* pbase = (int*)(w + o_pb);
    int* cur19 = (int*)(w + o_cur19);
    int* batchptr = (int*)(w + o_bp);
    unsigned* sdp = (unsigned*)(w + o_sdp);
    int* perm = (int*)(w + o_perm);
    unsigned* msg0 = (unsigned*)(w + o_msg0);
    int* dstoff = (int*)(w + o_doff);
    int* cur = (int*)(w + o_cur);
    int* part = (int*)(w + o_part);
    unsigned* wpk1 = (unsigned*)(w + o_wpk1);
    unsigned* wpk2 = (unsigned*)(w + o_wpk2);
    float* gate = (float*)(w + o_gate);
    unsigned* msg = (unsigned*)(w + o_msg);   // also aggh in fallback

    const int EB  = (NE + 255) / 256;        // 3125
    const int NW  = (NN + 3) / 4;            // 12500

    hipMemsetAsync(w, 0, use_store ? zero_small : zero_big, stream);

    // D1: etype hist (block-combined flush) || degree hist
    kd1<<<ET5 + EB5, 512, 0, stream>>>(dst, et, degi, cnt19);
    // D2: scanA || scan19+pad(+perm dump) || W pack
    kd2<<<SCB5 + 1 + WPB512, 512, 0, stream>>>(degi, part, cnt19, pbase, cur19, batchptr,
                                               hpk0, hpk1, sdp, perm, W1, W2, wpk1, wpk2);
    // D3: scanBC (dstoff + cur)
    kd3<<<SCB5, 512, 0, stream>>>(degi, part, dstoff, cur);
    // D4: fused scatter + CSR slot + perm + msg0
    kd4<<<EB5, 512, 0, stream>>>(src, dst, et, cur19, degi, cur, sdp, perm, msg0);

    if (use_store) {
        kf0m<<<NW, 256, 0, stream>>>(msg0, dstoff, W0, L0, b0, hpk0);

        // layer 1
        kmsgm<true><<<1024, 256, 0, stream>>>(sdp, perm, batchptr, hpk0, wpk1, msg);
        kfin<true, false, true><<<NW, 256, 0, stream>>>(msg, dstoff, hpk0, L1, b1, hpk1,
                                                        nullptr, nullptr, nullptr, nullptr, nullptr);
        // layer 2
        kmsgm<true><<<1024, 256, 0, stream>>>(sdp, perm, batchptr, hpk1, wpk2, msg);
        kfin<false, true, true><<<NW, 256, 0, stream>>>(msg, dstoff, hpk1, L2, b2, nullptr,
                                                        embp, nuc, gatew, gateb, gate);
    } else {
        // fallback: pk-f16 atomic aggregation
        ktpass<<<EB, 256, 0, stream>>>(src, dst, et, degi, T);
        kf0<<<NW, 256, 0, stream>>>(T, W0, L0, b0, degi, hpk0);
        hipMemsetAsync(msg, 0, (size_t)NN * 32 * 4, stream);
        kmsgm<false><<<1024, 256, 0, stream>>>(sdp, nullptr, batchptr, hpk0, wpk1, msg);
        kfin<true, false, false><<<NW, 256, 0, stream>>>(msg, nullptr, hpk0, L1, b1, hpk1,
                                                         nullptr, nullptr, nullptr, nullptr, nullptr);
        hipMemsetAsync(msg, 0, (size_t)NN * 32 * 4, stream);
        kmsgm<false><<<1024, 256, 0, stream>>>(sdp, nullptr, batchptr, hpk1, wpk2, msg);
        kfin<false, true, false><<<NW, 256, 0, stream>>>(msg, nullptr, hpk1, L2, b2, nullptr,
                                                         embp, nuc, gatew, gateb, gate);
    }

    // fused pooling + MLP
    kpoolmlp<<<NG, 128, 0, stream>>>(n2g, gate, embp, A1, ab1, A2, ab2, out0);
}